// Round 2
// baseline (729.300 us; speedup 1.0000x reference)
//
#include <hip/hip_runtime.h>
#include <hip/hip_fp16.h>

#define VOCAB 32000
#define D 256
#define NSTEPS 12
#define BATCH 8
#define SEQ 512

// scan chunking: chunk 0 = pos [0, CHUNK0) exact; chunk c>=1 covers
// [CHUNK0+(c-1)*CLEN, +CLEN) with WARM warm-up positions from prev=0.
// Warm-up influence decays ~ prod 12/(p+1) over WARM hops (<1e-4 at pos>=32).
#define CHUNK0 32
#define CLEN 8
#define WARM 12
#define NCHUNK (1 + (SEQ - CHUNK0) / CLEN)   // 61 -> 488 blocks -> 2 blocks/CU

typedef _Float16 f16x8 __attribute__((ext_vector_type(8)));
typedef float f32x4 __attribute__((ext_vector_type(4)));

// gelu(x) = 0.5 x (1 + erf(x/sqrt(2))); erf via A&S 7.1.26 (|err|<=1.5e-7).
// ~16 VALU inst vs ~60-70 for libm erff (which pays both branches).
__device__ __forceinline__ float gelu_fast(float x) {
    float y = x * 0.70710678118654752440f;
    float a = fabsf(y);
    float t = __builtin_amdgcn_rcpf(fmaf(0.3275911f, a, 1.0f));
    float p = fmaf(t, 1.061405429f, -1.453152027f);
    p = fmaf(t, p, 1.421413741f);
    p = fmaf(t, p, -0.284496736f);
    p = fmaf(t, p, 0.254829592f);
    p *= t;
    float e = __expf(-a * a);
    float erf_a = fmaf(-p, e, 1.0f);          // erf(|y|)
    float erf_y = copysignf(erf_a, y);
    return 0.5f * x * (1.0f + erf_y);
}

// ---------------------------------------------------------------------------
// Phase A: embedding gather + chunked positional scan.
// One block = (chunk, batch). 1024 threads: thread t -> element i = t>>2,
// j-chunk c = t&3 (64 j's each). W rows in VGPRs (16 float4/thread).
// State [256] f32 broadcast via LDS, 4 chunks of 64 padded to 68 f32.
// Each thread keeps its own element's state in a register (all threads hold
// the full dot after the quad shfl-reduce).
// ---------------------------------------------------------------------------
__global__ __launch_bounds__(1024) void scan_kernel(
    const int* __restrict__ ids, const float* __restrict__ emb,
    const float* __restrict__ W, const float* __restrict__ ps,
    float* __restrict__ states)
{
    const int chunk = blockIdx.x;
    const int b = blockIdx.y;
    const int t = (int)threadIdx.x;
    const int i = t >> 2;      // output element 0..255
    const int c = t & 3;       // j-chunk 0..3

    float4 w[16];
    {
        const float4* wrow = (const float4*)(W + i * D + c * 64);
        #pragma unroll
        for (int r = 0; r < 16; ++r) w[r] = wrow[r];
    }

    __shared__ float sbuf[2][4 * 68];

    int first_out, pstart, pend;
    if (chunk == 0) { first_out = 0; pstart = 0; pend = CHUNK0; }
    else {
        first_out = CHUNK0 + (chunk - 1) * CLEN;
        pstart = first_out - WARM;
        pend = first_out + CLEN;
    }

    float psr[NSTEPS];
    #pragma unroll
    for (int s = 0; s < NSTEPS; ++s) psr[s] = ps[s];

    const int saddr  = c * 68;                      // broadcast read chunk base
    const int myaddr = (i >> 6) * 68 + (i & 63);    // where element i lives

    float prev = 0.0f;

    for (int pos = pstart; pos < pend; ++pos) {
        int id = ids[b * SEQ + pos];
        float cur = emb[(size_t)id * D + i];
        float ctx = (pos > 0) ? (1.0f / (float)(pos + 1)) : 0.0f;
        if (c == 0) sbuf[0][myaddr] = cur;
        __syncthreads();
        #pragma unroll
        for (int s = 0; s < NSTEPS; ++s) {
            const int rb = s & 1;          // even steps read buf0
            const float4* sc = (const float4*)&sbuf[rb][saddr];
            float ax = 0.f, ay = 0.f, az = 0.f, aw = 0.f;
            #pragma unroll
            for (int r = 0; r < 16; ++r) {
                float4 sv = sc[r];
                ax = fmaf(sv.x, w[r].x, ax);
                ay = fmaf(sv.y, w[r].y, ay);
                az = fmaf(sv.z, w[r].z, az);
                aw = fmaf(sv.w, w[r].w, aw);
            }
            float dot = (ax + ay) + (az + aw);
            dot += __shfl_xor(dot, 1);
            dot += __shfl_xor(dot, 2);     // all 4 quad lanes hold full dot
            float x = fmaf(psr[s], cur, dot);
            cur = gelu_fast(x) + ctx * prev;
            if (c == 0) sbuf[rb ^ 1][myaddr] = cur;
            __syncthreads();
        }
        prev = cur;   // NSTEPS even -> next pos reads buf0 again
        if (pos >= first_out && c == 0)
            states[((size_t)(b * SEQ + pos)) * D + i] = cur;
    }
}

// ---------------------------------------------------------------------------
// Phase B: C[4096][32000] = states @ out_W^T + out_b, f32 via fp16-split MFMA
// (hi*hi + hi*lo + lo*hi), 128x128x64 tiles, 8 waves (2x4), wave tile 64x32.
// LDS tiles XOR-swizzled: byte ^= (row&7)<<4.
// ---------------------------------------------------------------------------
#define BM 128
#define BN 128
#define BK 64
#define GT 512

__device__ __forceinline__ void split8(float4 a, float4 b, f16x8& hi, f16x8& lo) {
    float v[8] = {a.x, a.y, a.z, a.w, b.x, b.y, b.z, b.w};
    #pragma unroll
    for (int j = 0; j < 8; ++j) {
        _Float16 h = (_Float16)v[j];
        hi[j] = h;
        lo[j] = (_Float16)(v[j] - (float)h);
    }
}

__global__ __launch_bounds__(GT) void gemm_kernel(
    const float* __restrict__ A,    // [4096][256] states
    const float* __restrict__ Bw,   // [32000][256] out_W
    const float* __restrict__ bias, // [32000]
    float* __restrict__ C)          // [4096][32000]
{
    __shared__ _Float16 __align__(16) Ahi[BM * BK], Alo[BM * BK];
    __shared__ _Float16 __align__(16) Bhi[BN * BK], Blo[BN * BK];

    const int tid = (int)threadIdx.x;
    const int bn = blockIdx.x, bm = blockIdx.y;
    const int lane = tid & 63, wave = tid >> 6;
    const int wm = wave >> 2, wn = wave & 3;      // 2 x 4 wave grid
    const int l15 = lane & 15, lh = lane >> 4;

    const int sr = tid >> 2;     // staging row 0..127
    const int sg = tid & 3;      // staging k-group (16 f32 each)

    f32x4 acc[4][2] = {};

    for (int kt = 0; kt < D; kt += BK) {
        {
            const float* asrc = A  + (size_t)(bm * BM + sr) * D + kt + sg * 16;
            const float* bsrc = Bw + (size_t)(bn * BN + sr) * D + kt + sg * 16;
            float4 av[4], bv[4];
            #pragma unroll
            for (int q = 0; q < 4; ++q) {
                av[q] = ((const float4*)asrc)[q];
                bv[q] = ((const float4*)bsrc)[q];
            }
            const int swz = (sr & 7) << 4;
            #pragma unroll
            for (int h = 0; h < 2; ++h) {
                const int off = (sr * 128 + sg * 32 + h * 16) ^ swz;
                f16x8 hi, lo;
                split8(av[h * 2], av[h * 2 + 1], hi, lo);
                *(f16x8*)((char*)Ahi + off) = hi;
                *(f16x8*)((char*)Alo + off) = lo;
                split8(bv[h * 2], bv[h * 2 + 1], hi, lo);
                *(f16x8*)((char*)Bhi + off) = hi;
                *(f16x8*)((char*)Blo + off) = lo;
            }
        }
        __syncthreads();
        #pragma unroll
        for (int ks = 0; ks < 2; ++ks) {
            f16x8 ah[4], al[4], bh[2], bl[2];
            #pragma unroll
            for (int mt = 0; mt < 4; ++mt) {
                const int row = wm * 64 + mt * 16 + l15;
                const int off = (row * 128 + ks * 64 + lh * 16) ^ ((row & 7) << 4);
                ah[mt] = *(const f16x8*)((const char*)Ahi + off);
                al[mt] = *(const f16x8*)((const char*)Alo + off);
            }
            #pragma unroll
            for (int nt = 0; nt < 2; ++nt) {
                const int row = wn * 32 + nt * 16 + l15;
                const int off = (row * 128 + ks * 64 + lh * 16) ^ ((row & 7) << 4);
                bh[nt] = *(const f16x8*)((const char*)Bhi + off);
                bl[nt] = *(const f16x8*)((const char*)Blo + off);
            }
            #pragma unroll
            for (int mt = 0; mt < 4; ++mt)
                #pragma unroll
                for (int nt = 0; nt < 2; ++nt) {
                    acc[mt][nt] = __builtin_amdgcn_mfma_f32_16x16x32_f16(ah[mt], bh[nt], acc[mt][nt], 0, 0, 0);
                    acc[mt][nt] = __builtin_amdgcn_mfma_f32_16x16x32_f16(ah[mt], bl[nt], acc[mt][nt], 0, 0, 0);
                    acc[mt][nt] = __builtin_amdgcn_mfma_f32_16x16x32_f16(al[mt], bh[nt], acc[mt][nt], 0, 0, 0);
                }
        }
        __syncthreads();
    }

    #pragma unroll
    for (int nt = 0; nt < 2; ++nt) {
        const int col = bn * BN + wn * 32 + nt * 16 + l15;
        const float bv = bias[col];
        #pragma unroll
        for (int mt = 0; mt < 4; ++mt) {
            const int row0 = bm * BM + wm * 64 + mt * 16 + lh * 4;
            #pragma unroll
            for (int r = 0; r < 4; ++r)
                C[(size_t)(row0 + r) * VOCAB + col] = acc[mt][nt][r] + bv;
        }
    }
}

extern "C" void kernel_launch(void* const* d_in, const int* in_sizes, int n_in,
                              void* d_out, int out_size, void* d_ws, size_t ws_size,
                              hipStream_t stream)
{
    const int*   ids  = (const int*)d_in[0];
    const float* emb  = (const float*)d_in[1];
    const float* W    = (const float*)d_in[2];
    const float* ps   = (const float*)d_in[3];
    const float* outW = (const float*)d_in[4];
    const float* outb = (const float*)d_in[5];
    float* out    = (float*)d_out;
    float* states = (float*)d_ws;   // [BATCH*SEQ][D] f32 = 4 MB

    scan_kernel<<<dim3(NCHUNK, BATCH), 1024, 0, stream>>>(ids, emb, W, ps, states);
    gemm_kernel<<<dim3(VOCAB / BN, (BATCH * SEQ) / BM), GT, 0, stream>>>(states, outW, outb, out);
}

// Round 3
// 498.808 us; speedup vs baseline: 1.4621x; 1.4621x over previous
//
#include <hip/hip_runtime.h>
#include <hip/hip_fp16.h>

#define VOCAB 32000
#define D 256
#define NSTEPS 12
#define BATCH 8
#define SEQ 512

// scan chunking (R0 config): chunk 0 = pos [0,32) exact; chunk c>=1 covers
// [32+(c-1)*16, +16) with 16 warm-up positions from prev=0.
#define CHUNK0 32
#define CLEN 16
#define WARM 16
#define NCHUNK (1 + (SEQ - CHUNK0) / CLEN)   // 31 -> 248 blocks, 1/CU

typedef _Float16 f16x8 __attribute__((ext_vector_type(8)));
typedef float f32x4 __attribute__((ext_vector_type(4)));

// gelu(x) = 0.5 x (1 + erf(x/sqrt(2))); erf via A&S 7.1.26 (|err|<=1.5e-7).
__device__ __forceinline__ float gelu_fast(float x) {
    float y = x * 0.70710678118654752440f;
    float a = fabsf(y);
    float t = __builtin_amdgcn_rcpf(fmaf(0.3275911f, a, 1.0f));
    float p = fmaf(t, 1.061405429f, -1.453152027f);
    p = fmaf(t, p, 1.421413741f);
    p = fmaf(t, p, -0.284496736f);
    p = fmaf(t, p, 0.254829592f);
    p *= t;
    float e = __expf(-a * a);
    float erf_y = copysignf(fmaf(-p, e, 1.0f), y);
    return 0.5f * x * (1.0f + erf_y);
}

// cross-lane helpers: xor1/xor2 via DPP quad_perm (VALU), xor4/xor8 via ds_swizzle
__device__ __forceinline__ float dpp_xor1(float v) {
    int r = __builtin_amdgcn_update_dpp(0, __float_as_int(v), 0xB1, 0xf, 0xf, true);
    return __int_as_float(r);
}
__device__ __forceinline__ float dpp_xor2(float v) {
    int r = __builtin_amdgcn_update_dpp(0, __float_as_int(v), 0x4E, 0xf, 0xf, true);
    return __int_as_float(r);
}
__device__ __forceinline__ float swz_xor4(float v) {
    return __int_as_float(__builtin_amdgcn_ds_swizzle(__float_as_int(v), 0x101F));
}
__device__ __forceinline__ float swz_xor8(float v) {
    return __int_as_float(__builtin_amdgcn_ds_swizzle(__float_as_int(v), 0x201F));
}

// ---------------------------------------------------------------------------
// Phase A scan, register-blocked O=4/J=16:
// thread t -> (og = t>>4, jc = t&15): computes outputs og*4..+3 over
// j in [jc*16, jc*16+16). W block (4x16) in VGPRs. State broadcast from LDS,
// 16 chunks of 16 f32 at stride 20 (bank-spread, 2-way max). Partial dots
// reduced across the 16 jc-lanes: xor1/xor2 DPP + xor4/xor8 swizzle with
// keep/send combining -> lane ends owning element og*4+(jc&3) in register.
// Lanes jc<4 are the writers (one replica per element).
// ---------------------------------------------------------------------------
__global__ __launch_bounds__(1024) void scan_kernel(
    const int* __restrict__ ids, const float* __restrict__ emb,
    const float* __restrict__ W, const float* __restrict__ ps,
    float* __restrict__ states)
{
    const int chunk = blockIdx.x;
    const int b = blockIdx.y;
    const int t = (int)threadIdx.x;
    const int og = t >> 4;             // 0..63
    const int jc = t & 15;             // 0..15
    const int i_mine = og * 4 + (jc & 3);
    const bool writer = (jc < 4);

    // W[og*4+m][jc*16 + q*4 .. +3]
    float4 wreg[4][4];
    #pragma unroll
    for (int m = 0; m < 4; ++m) {
        const float4* wrow = (const float4*)(W + (og * 4 + m) * D + jc * 16);
        #pragma unroll
        for (int q = 0; q < 4; ++q) wreg[m][q] = wrow[q];
    }

    __shared__ __align__(16) float sbuf[2][16 * 20];

    int first_out, pstart, pend;
    if (chunk == 0) { first_out = 0; pstart = 0; pend = CHUNK0; }
    else {
        first_out = CHUNK0 + (chunk - 1) * CLEN;
        pstart = first_out - WARM;
        pend = first_out + CLEN;
    }

    float psr[NSTEPS];
    #pragma unroll
    for (int s = 0; s < NSTEPS; ++s) psr[s] = ps[s];

    const int raddr = jc * 20;                                   // read base (f32)
    const int waddr = (i_mine >> 4) * 20 + (i_mine & 15);        // writer slot

    float prev = 0.0f;
    float cur = emb[(size_t)ids[b * SEQ + pstart] * D + i_mine];

    for (int pos = pstart; pos < pend; ++pos) {
        float nxt = 0.0f;
        if (pos + 1 < pend)
            nxt = emb[(size_t)ids[b * SEQ + pos + 1] * D + i_mine];  // prefetch
        const float ctx = (pos > 0) ? (1.0f / (float)(pos + 1)) : 0.0f;
        if (writer) sbuf[0][waddr] = cur;
        __syncthreads();
        #pragma unroll
        for (int s = 0; s < NSTEPS; ++s) {
            const int rb = s & 1;
            const float4* sp = (const float4*)&sbuf[rb][raddr];
            float4 s0 = sp[0], s1 = sp[1], s2 = sp[2], s3 = sp[3];
            float a0 = 0.f, a1 = 0.f, a2 = 0.f, a3 = 0.f;
            #pragma unroll
            for (int q = 0; q < 4; ++q) {
                float4 sv = (q == 0) ? s0 : (q == 1) ? s1 : (q == 2) ? s2 : s3;
                a0 = fmaf(sv.x, wreg[0][q].x, a0); a0 = fmaf(sv.y, wreg[0][q].y, a0);
                a0 = fmaf(sv.z, wreg[0][q].z, a0); a0 = fmaf(sv.w, wreg[0][q].w, a0);
                a1 = fmaf(sv.x, wreg[1][q].x, a1); a1 = fmaf(sv.y, wreg[1][q].y, a1);
                a1 = fmaf(sv.z, wreg[1][q].z, a1); a1 = fmaf(sv.w, wreg[1][q].w, a1);
                a2 = fmaf(sv.x, wreg[2][q].x, a2); a2 = fmaf(sv.y, wreg[2][q].y, a2);
                a2 = fmaf(sv.z, wreg[2][q].z, a2); a2 = fmaf(sv.w, wreg[2][q].w, a2);
                a3 = fmaf(sv.x, wreg[3][q].x, a3); a3 = fmaf(sv.y, wreg[3][q].y, a3);
                a3 = fmaf(sv.z, wreg[3][q].z, a3); a3 = fmaf(sv.w, wreg[3][q].w, a3);
            }
            // L1 (xor1): keep/send selection by jc&1
            float k01 = (jc & 1) ? a1 : a0, s01 = (jc & 1) ? a0 : a1;
            float r01 = k01 + dpp_xor1(s01);
            float k23 = (jc & 1) ? a3 : a2, s23 = (jc & 1) ? a2 : a3;
            float r23 = k23 + dpp_xor1(s23);
            // L2 (xor2): selection by jc&2
            float k = (jc & 2) ? r23 : r01, sx = (jc & 2) ? r01 : r23;
            float v = k + dpp_xor2(sx);
            // L3/L4: plain xor butterflies
            v += swz_xor4(v);
            v += swz_xor8(v);
            // v = full dot for element i_mine (replicated over jc>>2)
            float x = fmaf(psr[s], cur, v);
            cur = gelu_fast(x) + ctx * prev;
            if (writer) sbuf[rb ^ 1][waddr] = cur;
            __syncthreads();
        }
        prev = cur;   // NSTEPS even
        if (pos >= first_out && writer)
            states[((size_t)(b * SEQ + pos)) * D + i_mine] = cur;
        cur = nxt;
    }
}

// ---------------------------------------------------------------------------
// Phase B: C[4096][32000] = states @ out_W^T + out_b, f32 via fp16-split MFMA
// (hi*hi + hi*lo + lo*hi), 128x128x64 tiles, 8 waves (2x4), wave tile 64x32.
// LDS tiles XOR-swizzled: byte ^= (row&7)<<4.   (unchanged from R1)
// ---------------------------------------------------------------------------
#define BM 128
#define BN 128
#define BK 64
#define GT 512

__device__ __forceinline__ void split8(float4 a, float4 b, f16x8& hi, f16x8& lo) {
    float v[8] = {a.x, a.y, a.z, a.w, b.x, b.y, b.z, b.w};
    #pragma unroll
    for (int j = 0; j < 8; ++j) {
        _Float16 h = (_Float16)v[j];
        hi[j] = h;
        lo[j] = (_Float16)(v[j] - (float)h);
    }
}

__global__ __launch_bounds__(GT) void gemm_kernel(
    const float* __restrict__ A,    // [4096][256] states
    const float* __restrict__ Bw,   // [32000][256] out_W
    const float* __restrict__ bias, // [32000]
    float* __restrict__ C)          // [4096][32000]
{
    __shared__ _Float16 __align__(16) Ahi[BM * BK], Alo[BM * BK];
    __shared__ _Float16 __align__(16) Bhi[BN * BK], Blo[BN * BK];

    const int tid = (int)threadIdx.x;
    const int bn = blockIdx.x, bm = blockIdx.y;
    const int lane = tid & 63, wave = tid >> 6;
    const int wm = wave >> 2, wn = wave & 3;
    const int l15 = lane & 15, lh = lane >> 4;

    const int sr = tid >> 2;
    const int sg = tid & 3;

    f32x4 acc[4][2] = {};

    for (int kt = 0; kt < D; kt += BK) {
        {
            const float* asrc = A  + (size_t)(bm * BM + sr) * D + kt + sg * 16;
            const float* bsrc = Bw + (size_t)(bn * BN + sr) * D + kt + sg * 16;
            float4 av[4], bv[4];
            #pragma unroll
            for (int q = 0; q < 4; ++q) {
                av[q] = ((const float4*)asrc)[q];
                bv[q] = ((const float4*)bsrc)[q];
            }
            const int swz = (sr & 7) << 4;
            #pragma unroll
            for (int h = 0; h < 2; ++h) {
                const int off = (sr * 128 + sg * 32 + h * 16) ^ swz;
                f16x8 hi, lo;
                split8(av[h * 2], av[h * 2 + 1], hi, lo);
                *(f16x8*)((char*)Ahi + off) = hi;
                *(f16x8*)((char*)Alo + off) = lo;
                split8(bv[h * 2], bv[h * 2 + 1], hi, lo);
                *(f16x8*)((char*)Bhi + off) = hi;
                *(f16x8*)((char*)Blo + off) = lo;
            }
        }
        __syncthreads();
        #pragma unroll
        for (int ks = 0; ks < 2; ++ks) {
            f16x8 ah[4], al[4], bh[2], bl[2];
            #pragma unroll
            for (int mt = 0; mt < 4; ++mt) {
                const int row = wm * 64 + mt * 16 + l15;
                const int off = (row * 128 + ks * 64 + lh * 16) ^ ((row & 7) << 4);
                ah[mt] = *(const f16x8*)((const char*)Ahi + off);
                al[mt] = *(const f16x8*)((const char*)Alo + off);
            }
            #pragma unroll
            for (int nt = 0; nt < 2; ++nt) {
                const int row = wn * 32 + nt * 16 + l15;
                const int off = (row * 128 + ks * 64 + lh * 16) ^ ((row & 7) << 4);
                bh[nt] = *(const f16x8*)((const char*)Bhi + off);
                bl[nt] = *(const f16x8*)((const char*)Blo + off);
            }
            #pragma unroll
            for (int mt = 0; mt < 4; ++mt)
                #pragma unroll
                for (int nt = 0; nt < 2; ++nt) {
                    acc[mt][nt] = __builtin_amdgcn_mfma_f32_16x16x32_f16(ah[mt], bh[nt], acc[mt][nt], 0, 0, 0);
                    acc[mt][nt] = __builtin_amdgcn_mfma_f32_16x16x32_f16(ah[mt], bl[nt], acc[mt][nt], 0, 0, 0);
                    acc[mt][nt] = __builtin_amdgcn_mfma_f32_16x16x32_f16(al[mt], bh[nt], acc[mt][nt], 0, 0, 0);
                }
        }
        __syncthreads();
    }

    #pragma unroll
    for (int nt = 0; nt < 2; ++nt) {
        const int col = bn * BN + wn * 32 + nt * 16 + l15;
        const float bv = bias[col];
        #pragma unroll
        for (int mt = 0; mt < 4; ++mt) {
            const int row0 = bm * BM + wm * 64 + mt * 16 + lh * 4;
            #pragma unroll
            for (int r = 0; r < 4; ++r)
                C[(size_t)(row0 + r) * VOCAB + col] = acc[mt][nt][r] + bv;
        }
    }
}

extern "C" void kernel_launch(void* const* d_in, const int* in_sizes, int n_in,
                              void* d_out, int out_size, void* d_ws, size_t ws_size,
                              hipStream_t stream)
{
    const int*   ids  = (const int*)d_in[0];
    const float* emb  = (const float*)d_in[1];
    const float* W    = (const float*)d_in[2];
    const float* ps   = (const float*)d_in[3];
    const float* outW = (const float*)d_in[4];
    const float* outb = (const float*)d_in[5];
    float* out    = (float*)d_out;
    float* states = (float*)d_ws;   // [BATCH*SEQ][D] f32 = 4 MB

    scan_kernel<<<dim3(NCHUNK, BATCH), 1024, 0, stream>>>(ids, emb, W, ps, states);
    gemm_kernel<<<dim3(VOCAB / BN, (BATCH * SEQ) / BM), GT, 0, stream>>>(states, outW, outb, out);
}